// Round 6
// baseline (1663.324 us; speedup 1.0000x reference)
//
#include <hip/hip_runtime.h>
#include <cstddef>

// ---------------------------------------------------------------------------
// Agent LSTM PPO forward, MI355X — round 6 (identical resubmit of round 5;
// the bench infra timed out before that kernel ever ran — no evidence to
// act on, so no blind edits).
//
// Design (from r4 post-mortem: VGPR_Count=128 proved the 192-reg fp8 weight
// array spilled to scratch; step time matched L2-scratch BW ~6.5K cyc; and
// the MFMA budget was mis-scaled — 16x16 rate is ~4.9 cyc/MFMA PER CU):
//  * i8 16x16x64 MFMA (K=64, ~5.1 cyc/MFMA) -> 384 MFMA/CU-step ~1960 cyc.
//    Quant: W x1024, A (x and h) x32, dequant 1/32768. i8 err <= fp8 err.
//  * col-remap: wave wv owns units [wv*32, wv*32+32) of ALL 4 gates
//    (8 tiles). Nonlin reads acc REGISTERS directly -> no gate LDS,
//    ONE barrier/step (x/h ping-pong in LDS).
//  * spill-proof: 6 tiles (f,i,c) weights in regs = 144 VGPR; o-gate's
//    2 tiles streamed from LDS (16 slots x 6.4KB = 102.4KB, 400B-pad
//    col-major, ~2-way conflicts = free). Peak pressure ~220 << 256 cap.
//  * lanes lg>=2 stage+quantize x_{t+1} while lanes lg<2 run nonlin.
// ---------------------------------------------------------------------------

#define S_LEN 512
#define OBS_D 128
#define HIDN  256
#define BATCH 256
#define ROWS  8
#define NWG   32
#define ACT_DIM 32

// dynamic LDS layout (bytes)
#define XW_OFF   0                      // o-gate weights: 16 slots x 6400
#define XW_BYTES (16 * 16 * 400)        // slot = wv*2+u; [slot][col l15][k pad 400]
#define XB_OFF   XW_BYTES               // x i8 ping-pong [2][16][144]
#define XB_BYTES (2 * 16 * 144)
#define HB_OFF   (XB_OFF + XB_BYTES)    // h i8 ping-pong [2][16][272]
#define HB_BYTES (2 * 16 * 272)
#define LDS_TOTAL (HB_OFF + HB_BYTES)   // 115712

typedef int   i32x4 __attribute__((ext_vector_type(4)));
typedef float f32x4 __attribute__((ext_vector_type(4)));

#define L2E 1.4426950408889634f
#define DQS (L2E / 32768.0f)            // dequant * log2(e)

__device__ __forceinline__ float sigexp2(float y) {
    // y pre-scaled by log2(e): sigmoid(x) = 1/(1+2^(-y))
    return __builtin_amdgcn_rcpf(1.0f + __builtin_amdgcn_exp2f(-y));
}
__device__ __forceinline__ int q8(float v) {
    float c = fmaxf(-127.0f, fminf(127.0f, v));
    return ((int)__builtin_rintf(c)) & 255;
}

extern __shared__ char smem[];

__global__ void __launch_bounds__(512, 2)
lstm_fused(const float* __restrict__ obs,
           const float* __restrict__ Wfp, const float* __restrict__ bfp,
           const float* __restrict__ Wip, const float* __restrict__ bip,
           const float* __restrict__ Wcp, const float* __restrict__ bcp,
           const float* __restrict__ Wop, const float* __restrict__ bop,
           float* __restrict__ hfinal)          // [BATCH][HIDN] f32
{
    const int tid  = threadIdx.x;
    const int wv   = tid >> 6;
    const int lane = tid & 63;
    const int l15  = lane & 15, lg = lane >> 4;
    const int b0   = blockIdx.x * ROWS;

    // ---- phase 0: zero x/h ping-pong buffers; write o-gate LDS weights ---
    {
        int* zp = (int*)(smem + XB_OFF);
        for (int i = tid; i < (XB_BYTES + HB_BYTES) / 4; i += 512) zp[i] = 0;
    }
    {
#pragma unroll
        for (int u = 0; u < 2; ++u) {
            const int col = wv * 32 + u * 16 + l15;
            const float* src = Wop + col;
            char* dst = smem + XW_OFF + (size_t)(wv * 2 + u) * 6400
                      + l15 * 400 + lg * 96;
#pragma unroll
            for (int j = 0; j < 24; ++j) {
                const int k0 = lg * 96 + j * 4;
                const int b = q8(src[(size_t)(k0 + 0) * HIDN] * 1024.f)
                           | (q8(src[(size_t)(k0 + 1) * HIDN] * 1024.f) << 8)
                           | (q8(src[(size_t)(k0 + 2) * HIDN] * 1024.f) << 16)
                           | (q8(src[(size_t)(k0 + 3) * HIDN] * 1024.f) << 24);
                *(int*)(dst + j * 4) = b;
            }
        }
    }

    // ---- register weights: tiles 0..5 = gates f,i,c (jt=tau&1) -----------
    i32x4 wfr[6][6];                    // [tile][kk], k = kk*64 + lg*16 + e
#pragma unroll
    for (int tt = 0; tt < 6; ++tt) {
        const int g = tt >> 1, jt = tt & 1;
        const int col = wv * 32 + jt * 16 + l15;
        const float* src = ((g == 0) ? Wfp : (g == 1) ? Wip : Wcp) + col;
#pragma unroll
        for (int kk = 0; kk < 6; ++kk) {
            i32x4 v;
#pragma unroll
            for (int w = 0; w < 4; ++w) {
                const int k0 = kk * 64 + lg * 16 + w * 4;
                v[w] = q8(src[(size_t)(k0 + 0) * HIDN] * 1024.f)
                     | (q8(src[(size_t)(k0 + 1) * HIDN] * 1024.f) << 8)
                     | (q8(src[(size_t)(k0 + 2) * HIDN] * 1024.f) << 16)
                     | (q8(src[(size_t)(k0 + 3) * HIDN] * 1024.f) << 24);
            }
            wfr[tt][kk] = v;
        }
    }

    // ---- per-lane biases (pre-scaled by log2e; c-gate x2) ----------------
    float bF[2], bI[2], bC[2], bO[2];
#pragma unroll
    for (int jt = 0; jt < 2; ++jt) {
        const int u = wv * 32 + jt * 16 + l15;
        bF[jt] = bfp[u] * L2E;
        bI[jt] = bip[u] * L2E;
        bC[jt] = bcp[u] * (2.0f * L2E);
        bO[jt] = bop[u] * L2E;
    }

    f32x4 cr0 = {0.f, 0.f, 0.f, 0.f};   // c-state jt=0: rows lg*4+q
    f32x4 cr1 = {0.f, 0.f, 0.f, 0.f};   // c-state jt=1

    __syncthreads();                     // zero done before x0 staging

    // ---- x staging setup: lanes lg>=2 own row wv, elems sidx*4..+3 -------
    const int isStager = (lg >= 2);
    const int sidx = (lg - 2) * 16 + l15;           // 0..31 for stagers
    const float* xsrc = obs + (size_t)(b0 + wv) * S_LEN * OBS_D + sidx * 4;
    float4 xv = {0.f, 0.f, 0.f, 0.f};
    if (isStager) {
        const float4 x0 = *(const float4*)(xsrc);   // t = 0
        const int qp = q8(x0.x * 32.f) | (q8(x0.y * 32.f) << 8)
                     | (q8(x0.z * 32.f) << 16) | (q8(x0.w * 32.f) << 24);
        *(int*)(smem + XB_OFF + wv * 144 + sidx * 4) = qp;
        xv = *(const float4*)(xsrc + OBS_D);        // prefetch t = 1
    }
    __syncthreads();                     // x0/h0 visible

#pragma unroll 1
    for (int t = 0; t < S_LEN; ++t) {
        const int p = t & 1;
        const char* xrow = smem + XB_OFF + p * 2304 + l15 * 144 + lg * 16;
        const char* hrow = smem + HB_OFF + p * 4352 + l15 * 272 + lg * 16;
        const char* wl   = smem + XW_OFF + (size_t)wv * 12800 + l15 * 400 + lg * 16;

        i32x4 acc[8];
#pragma unroll
        for (int i2 = 0; i2 < 8; ++i2) acc[i2] = (i32x4){0, 0, 0, 0};

#pragma unroll
        for (int kk = 0; kk < 6; ++kk) {
            const i32x4 a = (kk < 2) ? *(const i32x4*)(xrow + kk * 64)
                                     : *(const i32x4*)(hrow + (kk - 2) * 64);
            const i32x4 b6 = *(const i32x4*)(wl + kk * 64);
            const i32x4 b7 = *(const i32x4*)(wl + 6400 + kk * 64);
            acc[0] = __builtin_amdgcn_mfma_i32_16x16x64_i8(a, wfr[0][kk], acc[0], 0, 0, 0);
            acc[1] = __builtin_amdgcn_mfma_i32_16x16x64_i8(a, wfr[1][kk], acc[1], 0, 0, 0);
            acc[2] = __builtin_amdgcn_mfma_i32_16x16x64_i8(a, wfr[2][kk], acc[2], 0, 0, 0);
            acc[3] = __builtin_amdgcn_mfma_i32_16x16x64_i8(a, wfr[3][kk], acc[3], 0, 0, 0);
            acc[4] = __builtin_amdgcn_mfma_i32_16x16x64_i8(a, wfr[4][kk], acc[4], 0, 0, 0);
            acc[5] = __builtin_amdgcn_mfma_i32_16x16x64_i8(a, wfr[5][kk], acc[5], 0, 0, 0);
            acc[6] = __builtin_amdgcn_mfma_i32_16x16x64_i8(a, b6, acc[6], 0, 0, 0);
            acc[7] = __builtin_amdgcn_mfma_i32_16x16x64_i8(a, b7, acc[7], 0, 0, 0);
        }

        if (isStager) {
            // write x_{t+1} (quantized from value prefetched last iter)
            const int qp = q8(xv.x * 32.f) | (q8(xv.y * 32.f) << 8)
                         | (q8(xv.z * 32.f) << 16) | (q8(xv.w * 32.f) << 24);
            *(int*)(smem + XB_OFF + (p ^ 1) * 2304 + wv * 144 + sidx * 4) = qp;
            if (t + 2 < S_LEN)
                xv = *(const float4*)(xsrc + (size_t)(t + 2) * OBS_D);
        } else {
            // nonlin on own accumulators: rows lg*4+q, units wv*32+jt*16+l15
#pragma unroll
            for (int jt = 0; jt < 2; ++jt) {
#pragma unroll
                for (int q = 0; q < 4; ++q) {
                    const float yf = fmaf((float)acc[0 + jt][q], DQS, bF[jt]);
                    const float yi = fmaf((float)acc[2 + jt][q], DQS, bI[jt]);
                    const float yc = fmaf((float)acc[4 + jt][q], 2.0f * DQS, bC[jt]);
                    const float yo = fmaf((float)acc[6 + jt][q], DQS, bO[jt]);
                    const float fv = sigexp2(yf);
                    const float iv = sigexp2(yi);
                    const float cv = 2.0f * sigexp2(yc) - 1.0f;   // tanh
                    const float ov = sigexp2(yo);
                    float c = (jt ? cr1[q] : cr0[q]);
                    c = fv * c + iv * cv;
                    if (jt) cr1[q] = c; else cr0[q] = c;
                    const float th = 2.0f * sigexp2(2.0f * L2E * c) - 1.0f;
                    const float hv = ov * th;
                    const int row = lg * 4 + q;
                    const int hq = ((int)__builtin_rintf(hv * 32.0f)) & 255;
                    *(unsigned char*)(smem + HB_OFF + (p ^ 1) * 4352
                                      + row * 272 + wv * 32 + jt * 16 + l15)
                        = (unsigned char)hq;
                    if (t == S_LEN - 1)
                        hfinal[(size_t)(b0 + row) * HIDN + wv * 32 + jt * 16 + l15] = hv;
                }
            }
        }
        __syncthreads();   // x_{t+1}/h_{t+1} ready; also fences next reads
    }
}

// ---------------------------------------------------------------------------
// Head: z1=relu(h@W1+b1), z2=relu(z1@W2+b2), actor/critic, log_softmax.
// 64 wgs x 4 batch rows. Unchanged (validated rounds 1-4).
// ---------------------------------------------------------------------------
__device__ __forceinline__ float tanh_f(float x) {
    return 2.0f / (1.0f + __expf(-2.0f * x)) - 1.0f;
}

__global__ void __launch_bounds__(256)
head_kernel(const float* __restrict__ hfin,      // [BATCH][HIDN] f32
            const float* __restrict__ W1, const float* __restrict__ b1v,
            const float* __restrict__ W2, const float* __restrict__ b2v,
            const float* __restrict__ A1, const float* __restrict__ a1v,
            const float* __restrict__ A2, const float* __restrict__ a2v,
            const float* __restrict__ A3, const float* __restrict__ a3v,
            const float* __restrict__ C1, const float* __restrict__ c1v,
            const float* __restrict__ C2, const float* __restrict__ c2v,
            const float* __restrict__ C3, const float* __restrict__ c3v,
            const int* __restrict__ action,
            float* __restrict__ out)             // [3][BATCH]
{
    __shared__ float e0[4][HIDN];
    __shared__ float z1s[4][512];
    __shared__ float z2s[4][512];
    __shared__ float aL[4][64], vL[4][64], a2L[4][64], v2L[4][64];
    __shared__ float lgL[4][ACT_DIM];
    __shared__ float valL[4];

    const int tid = threadIdx.x;
    const int b0 = blockIdx.x * 4;

    for (int idx = tid; idx < 4 * HIDN; idx += 256) {
        const int r = idx >> 8, k = idx & 255;
        e0[r][k] = hfin[(size_t)(b0 + r) * HIDN + k];
    }
    __syncthreads();

    for (int i = 0; i < 8; ++i) {
        const int idx = i * 256 + tid;
        const int r = idx >> 9, cc = idx & 511;
        float acc = b1v[cc];
#pragma unroll 8
        for (int k = 0; k < HIDN; ++k) acc = fmaf(e0[r][k], W1[k * 512 + cc], acc);
        z1s[r][cc] = fmaxf(acc, 0.0f);
    }
    __syncthreads();

    for (int i = 0; i < 8; ++i) {
        const int idx = i * 256 + tid;
        const int r = idx >> 9, cc = idx & 511;
        float acc = b2v[cc];
#pragma unroll 8
        for (int k = 0; k < 512; ++k) acc = fmaf(z1s[r][k], W2[k * 512 + cc], acc);
        z2s[r][cc] = fmaxf(acc, 0.0f);
    }
    __syncthreads();

    {
        const int r = tid >> 6, j = tid & 63;
        float acc = a1v[j], accv = c1v[j];
#pragma unroll 8
        for (int k = 0; k < 512; ++k) {
            const float e = z2s[r][k];
            acc  = fmaf(e, A1[k * 64 + j], acc);
            accv = fmaf(e, C1[k * 64 + j], accv);
        }
        aL[r][j] = tanh_f(acc);
        vL[r][j] = tanh_f(accv);
    }
    __syncthreads();
    {
        const int r = tid >> 6, j = tid & 63;
        float acc = a2v[j], accv = c2v[j];
#pragma unroll 8
        for (int k = 0; k < 64; ++k) {
            acc  = fmaf(aL[r][k], A2[k * 64 + j], acc);
            accv = fmaf(vL[r][k], C2[k * 64 + j], accv);
        }
        a2L[r][j] = tanh_f(acc);
        v2L[r][j] = tanh_f(accv);
    }
    __syncthreads();
    if (tid < 128) {
        const int r = tid >> 5, j = tid & 31;
        float acc = a3v[j];
#pragma unroll 8
        for (int k = 0; k < 64; ++k) acc = fmaf(a2L[r][k], A3[k * ACT_DIM + j], acc);
        lgL[r][j] = acc;
    }
    if (tid >= 128 && tid < 132) {
        const int r = tid - 128;
        float acc = c3v[0];
#pragma unroll 8
        for (int k = 0; k < 64; ++k) acc = fmaf(v2L[r][k], C3[k], acc);
        valL[r] = acc;
    }
    __syncthreads();

    {
        const int wv = tid >> 6, lane = tid & 63;
        const float x = (lane < ACT_DIM) ? lgL[wv][lane] : -3.4e38f;
        float m = x;
        for (int off = 32; off; off >>= 1) m = fmaxf(m, __shfl_xor(m, off));
        const float p = (lane < ACT_DIM) ? __expf(x - m) : 0.0f;
        float s = p;
        for (int off = 32; off; off >>= 1) s += __shfl_xor(s, off);
        const float logs = logf(s);
        const float lp = x - m - logs;
        const int act = action[b0 + wv];
        float sel = (lane == act) ? lp : 0.0f;
        for (int off = 32; off; off >>= 1) sel += __shfl_xor(sel, off);
        float et = (lane < ACT_DIM) ? p * lp : 0.0f;
        for (int off = 32; off; off >>= 1) et += __shfl_xor(et, off);
        if (lane == 0) {
            const int b = b0 + wv;
            out[b]             = sel;
            out[BATCH + b]     = -et / s;
            out[2 * BATCH + b] = valL[wv];
        }
    }
}

extern "C" void kernel_launch(void* const* d_in, const int* in_sizes, int n_in,
                              void* d_out, int out_size, void* d_ws, size_t ws_size,
                              hipStream_t stream) {
    const float* obs = (const float*)d_in[0];
    const int*   action = (const int*)d_in[1];
    const float* Wfp = (const float*)d_in[2];  const float* bfp = (const float*)d_in[3];
    const float* Wip = (const float*)d_in[4];  const float* bip = (const float*)d_in[5];
    const float* Wcp = (const float*)d_in[6];  const float* bcp = (const float*)d_in[7];
    const float* Wop = (const float*)d_in[8];  const float* bop = (const float*)d_in[9];
    const float* W1  = (const float*)d_in[10]; const float* b1v = (const float*)d_in[11];
    const float* W2  = (const float*)d_in[12]; const float* b2v = (const float*)d_in[13];
    const float* A1  = (const float*)d_in[14]; const float* a1v = (const float*)d_in[15];
    const float* A2  = (const float*)d_in[16]; const float* a2v = (const float*)d_in[17];
    const float* A3  = (const float*)d_in[18]; const float* a3v = (const float*)d_in[19];
    const float* C1  = (const float*)d_in[20]; const float* c1v = (const float*)d_in[21];
    const float* C2  = (const float*)d_in[22]; const float* c2v = (const float*)d_in[23];
    const float* C3  = (const float*)d_in[24]; const float* c3v = (const float*)d_in[25];

    float* hfinal = (float*)d_ws;   // 256KB, fully overwritten each call

    hipFuncSetAttribute((const void*)lstm_fused,
                        hipFuncAttributeMaxDynamicSharedMemorySize, LDS_TOTAL);

    lstm_fused<<<dim3(NWG), dim3(512), LDS_TOTAL, stream>>>(
        obs, Wfp, bfp, Wip, bip, Wcp, bcp, Wop, bop, hfinal);

    head_kernel<<<dim3(64), dim3(256), 0, stream>>>(
        hfinal, W1, b1v, W2, b2v, A1, a1v, A2, a2v, A3, a3v,
        C1, c1v, C2, c2v, C3, c3v, action, (float*)d_out);
}